// Round 6
// baseline (370.212 us; speedup 1.0000x reference)
//
#include <hip/hip_runtime.h>
#include <hip/hip_cooperative_groups.h>
#include <math.h>

namespace cg = cooperative_groups;

// B=2, L=2048, D=512, N=64 -> M=4096 tokens.
//   y[t,d] = x[t,d] * softplus((x@W1+b1)[t,d]) * s[t]
//   s[t]   = dot(x_t@W2+b2, x_t@W3+b3)
//   exp(delta*A) multiplies h=0 -> contributes zero; A unused.
//
// Single cooperative kernel, 512 blocks x 512 thr (exactly 2 blocks/CU).
//   phase0: W1/W2/W3 -> f16 fragment slabs (blocks 256..275); x -> f16 slabs
//           via LDS (blocks 0..255, one 16-token tile each)
//   sync
//   phase1: s[t] per tile (blocks 0..255; A-frags from still-resident LDS,
//           B/C-frags direct global->VGPR from w23 slabs)
//   sync
//   phase2: zero-LDS register GEMM y = x * softplus(x@W1+b1) * s (all blocks)
//
// Fragment slab = 16(rows)x32(k) f16 tile as 1024 contiguous bytes in exact
// MFMA lane order (lane L=q*16+m holds row m, k=q*8..q*8+7) -> every wave
// fragment load is a fully-coalesced 1KB read.
#define DDIM 512

typedef _Float16 f16;
typedef _Float16 f16x4 __attribute__((ext_vector_type(4)));
typedef _Float16 f16x8 __attribute__((ext_vector_type(8)));
typedef float f32x4 __attribute__((ext_vector_type(4)));

__device__ __forceinline__ float softplusf(float v) {
    return (v > 20.0f) ? v : log1pf(__expf(v));
}

__global__ __launch_bounds__(512, 4) void fused_kernel(
    const float* __restrict__ x,  const float* __restrict__ W1,
    const float* __restrict__ b1, const float* __restrict__ W2,
    const float* __restrict__ b2, const float* __restrict__ W3,
    const float* __restrict__ b3,
    f16* __restrict__ xh, f16* __restrict__ w1t, f16* __restrict__ w23,
    float* __restrict__ sv, float* __restrict__ y)
{
    __shared__ __align__(16) char smem[33536];
    f16 (*xs)[520]  = (f16(*)[520])smem;            // blocks < 256 (16.6 KB)
    f16 (*lt)[520]  = (f16(*)[520])smem;            // weight blocks (33.3 KB)
    float* sred     = (float*)(smem + 33280);       // 64 floats

    const int tid  = threadIdx.x;
    const int bid  = blockIdx.x;
    const int wv   = tid >> 6;
    const int lane = tid & 63;
    const int q    = lane >> 4;
    const int l15  = lane & 15;

    cg::grid_group grid = cg::this_grid();

    // ---------------- phase 0 ----------------
    if (bid < 256) {
        // x tile bid: 16 tokens -> f16 LDS, then 16 fragment slabs to xh
        const int tb  = bid * 16;
        const int row = tid >> 5;          // 0..15
        const int cg4 = (tid & 31) * 4;    // 0..124
        const float* xr = x + (size_t)(tb + row) * DDIM;
#pragma unroll
        for (int i = 0; i < 4; ++i) {
            int col = cg4 + i * 128;
            float4 v = *(const float4*)(xr + col);
            f16x4 h = {(f16)v.x, (f16)v.y, (f16)v.z, (f16)v.w};
            *(f16x4*)&xs[row][col] = h;
        }
        __syncthreads();
#pragma unroll
        for (int j = 0; j < 2; ++j) {
            int kt = wv * 2 + j;
            f16x8 vv = *(const f16x8*)&xs[l15][kt * 32 + q * 8];
            *(f16x8*)(xh + (size_t)(bid * 16 + kt) * 512 + lane * 8) = vv;
        }
    } else if (bid < 276) {
        // weight strip: 512 k x 32 cols, transpose-convert -> 32 slabs
        const int wb = bid - 256;
        const float* src; int srcRS, col0; f16* dst;
        if (wb < 16)      { src = W1; srcRS = DDIM; col0 = wb * 32;
                            dst = w1t + (size_t)wb * 2 * 16 * 512; }
        else if (wb < 18) { src = W2; srcRS = 64;  col0 = (wb - 16) * 32;
                            dst = w23 + (size_t)(wb - 16) * 2 * 16 * 512; }
        else              { src = W3; srcRS = 64;  col0 = (wb - 18) * 32;
                            dst = w23 + (size_t)(4 + (wb - 18) * 2) * 16 * 512; }
#pragma unroll
        for (int i = 0; i < 8; ++i) {
            int f  = tid + 512 * i;
            int k  = f >> 3;
            int c4 = (f & 7) * 4;
            float4 v = *(const float4*)(src + (size_t)k * srcRS + col0 + c4);
            lt[c4 + 0][k] = (f16)v.x; lt[c4 + 1][k] = (f16)v.y;
            lt[c4 + 2][k] = (f16)v.z; lt[c4 + 3][k] = (f16)v.w;
        }
        __syncthreads();
#pragma unroll
        for (int j = 0; j < 4; ++j) {
            int s   = wv * 4 + j;          // 0..31
            int ntL = s >> 4;
            int kt  = s & 15;
            f16x8 vv = *(const f16x8*)&lt[ntL * 16 + l15][kt * 32 + q * 8];
            *(f16x8*)(dst + (size_t)(ntL * 16 + kt) * 512 + lane * 8) = vv;
        }
    }

    __threadfence();
    grid.sync();

    // ---------------- phase 1: s ----------------
    if (bid < 256) {
        const int tb = bid * 16;
        if (wv < 4) {
            f32x4 acc0 = (f32x4){0.f, 0.f, 0.f, 0.f};
            f32x4 acc1 = (f32x4){0.f, 0.f, 0.f, 0.f};
            const f16* wB = w23 + (size_t)(wv    ) * 16 * 512 + lane * 8;
            const f16* wC = w23 + (size_t)(wv + 4) * 16 * 512 + lane * 8;
#pragma unroll
            for (int kt = 0; kt < 16; ++kt) {
                f16x8 a  = *(const f16x8*)&xs[l15][kt * 32 + q * 8];
                f16x8 bB = *(const f16x8*)(wB + (size_t)kt * 512);
                f16x8 bC = *(const f16x8*)(wC + (size_t)kt * 512);
                acc0 = __builtin_amdgcn_mfma_f32_16x16x32_f16(a, bB, acc0, 0, 0, 0);
                acc1 = __builtin_amdgcn_mfma_f32_16x16x32_f16(a, bC, acc1, 0, 0, 0);
            }
            float b2v = b2[wv * 16 + l15];
            float b3v = b3[wv * 16 + l15];
#pragma unroll
            for (int r = 0; r < 4; ++r) {
                float p = (acc0[r] + b2v) * (acc1[r] + b3v);
                p += __shfl_xor(p, 1); p += __shfl_xor(p, 2);
                p += __shfl_xor(p, 4); p += __shfl_xor(p, 8);
                if (l15 == 0) sred[wv * 16 + q * 4 + r] = p;
            }
        }
        __syncthreads();
        if (tid < 16)
            sv[tb + tid] = sred[tid] + sred[16 + tid] + sred[32 + tid] + sred[48 + tid];
    }

    __threadfence();
    grid.sync();

    // ---------------- phase 2: y (zero-LDS register GEMM) ----------------
    {
        const int cB = bid & 7;            // d-block (64 cols)
        const int rB = bid >> 3;           // token-block (64 rows)
        const int mt = wv & 3;
        const int nh = wv >> 2;

        const f16* aP  = xh  + (size_t)((rB * 4 + mt) * 16) * 512 + lane * 8;
        const f16* bP0 = w1t + (size_t)((cB * 4 + nh * 2 + 0) * 16) * 512 + lane * 8;
        const f16* bP1 = w1t + (size_t)((cB * 4 + nh * 2 + 1) * 16) * 512 + lane * 8;

        f32x4 acc0 = (f32x4){0.f, 0.f, 0.f, 0.f};
        f32x4 acc1 = (f32x4){0.f, 0.f, 0.f, 0.f};
#pragma unroll
        for (int kt = 0; kt < 16; ++kt) {
            f16x8 a  = *(const f16x8*)(aP  + (size_t)kt * 512);
            f16x8 b0 = *(const f16x8*)(bP0 + (size_t)kt * 512);
            f16x8 bb = *(const f16x8*)(bP1 + (size_t)kt * 512);
            acc0 = __builtin_amdgcn_mfma_f32_16x16x32_f16(a, b0, acc0, 0, 0, 0);
            acc1 = __builtin_amdgcn_mfma_f32_16x16x32_f16(a, bb, acc1, 0, 0, 0);
        }

        const int d0 = cB * 64 + (nh * 2 + 0) * 16 + l15;
        const int d1 = cB * 64 + (nh * 2 + 1) * 16 + l15;
        const float bb0 = b1[d0], bb1 = b1[d1];
#pragma unroll
        for (int r = 0; r < 4; ++r) {
            int token = rB * 64 + mt * 16 + q * 4 + r;
            float st = sv[token];
            const float* xr = x + (size_t)token * DDIM;
            float*       yr = y + (size_t)token * DDIM;
            yr[d0] = xr[d0] * softplusf(acc0[r] + bb0) * st;
            yr[d1] = xr[d1] * softplusf(acc1[r] + bb1) * st;
        }
    }
}

// ---------------------------------------------------------------------------
extern "C" void kernel_launch(void* const* d_in, const int* in_sizes, int n_in,
                              void* d_out, int out_size, void* d_ws, size_t ws_size,
                              hipStream_t stream)
{
    (void)n_in; (void)out_size; (void)ws_size; (void)in_sizes;
    const float* x  = (const float*)d_in[0];
    const float* W1 = (const float*)d_in[1];
    const float* b1 = (const float*)d_in[2];
    const float* W2 = (const float*)d_in[3];
    const float* b2 = (const float*)d_in[4];
    const float* W3 = (const float*)d_in[5];
    const float* b3 = (const float*)d_in[6];
    // d_in[7] = A unused (multiplies h=0)
    float* y = (float*)d_out;

    char* ws  = (char*)d_ws;
    f16* xh   = (f16*)(ws);                           // 4 MB   (256 tiles x 16 slabs)
    f16* w1t  = (f16*)(ws + (4 << 20));               // 512 KB (32 nt x 16 kt)
    f16* w23  = (f16*)(ws + (4 << 20) + (512 << 10)); // 128 KB (8 nt x 16 kt)
    float* sv = (float*)(ws + (5 << 20));             // 16 KB

    void* args[] = { (void*)&x, (void*)&W1, (void*)&b1, (void*)&W2, (void*)&b2,
                     (void*)&W3, (void*)&b3, (void*)&xh, (void*)&w1t, (void*)&w23,
                     (void*)&sv, (void*)&y };
    hipLaunchCooperativeKernel((const void*)fused_kernel,
                               dim3(512), dim3(512), args, 0, stream);
}

// Round 7
// 100.348 us; speedup vs baseline: 3.6893x; 3.6893x over previous
//
#include <hip/hip_runtime.h>
#include <math.h>

// B=2, L=2048, D=512, N=64 -> M=4096 tokens.
//   y[t,d] = x[t,d] * softplus((x@W1+b1)[t,d]) * s[t]
//   s[t]   = dot(x_t@W2+b2, x_t@W3+b3)
//   exp(delta*A) multiplies h=0 -> contributes zero; A unused.
//
// Two launches (cooperative grid.sync measured at ~140us/sync on R6 -- never
// again):
//   K1 (272 blocks): bid<256  -> 16-token tile: x->f16 LDS, xh fragment
//                    slabs for K2, s[t] via MFMA with W2/W3 B/C fragments
//                    built DIRECTLY from fp32 weights in registers (L2-hot,
//                    no transposed-weight dependency).
//                    bid>=256 -> W1 strip transpose-convert to w1t slabs
//                    (independent; consumed only by K2).
//   K2 (512 blocks): zero-LDS register GEMM y = x*softplus(x@W1+b1)*s; all
//                    fragments direct global->VGPR from pre-swizzled slabs.
//
// Fragment slab = 16(rows)x32(k) f16 tile as 1024 contiguous bytes in exact
// MFMA lane order (lane L=q*16+m holds row m, k=q*8..q*8+7) -> every wave
// fragment load is one fully-coalesced 1KB read.
#define DDIM 512

typedef _Float16 f16;
typedef _Float16 f16x4 __attribute__((ext_vector_type(4)));
typedef _Float16 f16x8 __attribute__((ext_vector_type(8)));
typedef float f32x4 __attribute__((ext_vector_type(4)));

__device__ __forceinline__ float softplusf(float v) {
    return (v > 20.0f) ? v : log1pf(__expf(v));
}

// ---------------------------------------------------------------------------
// K1: 272 blocks x 256 thr.
// ---------------------------------------------------------------------------
__global__ __launch_bounds__(256) void k1_s_and_prep(
    const float* __restrict__ x,  const float* __restrict__ W1,
    const float* __restrict__ W2, const float* __restrict__ b2,
    const float* __restrict__ W3, const float* __restrict__ b3,
    f16* __restrict__ xh, f16* __restrict__ w1t, float* __restrict__ s_out)
{
    __shared__ __align__(16) char smem[34048];
    f16 (*xs)[520] = (f16(*)[520])smem;          // x path: 16 rows  (16.6 KB)
    f16 (*lt)[520] = (f16(*)[520])smem;          // W1 path: 32 rows (33.3 KB)
    float* sred    = (float*)(smem + 33536);     // 64 floats

    const int tid  = threadIdx.x;
    const int bid  = blockIdx.x;
    const int wv   = tid >> 6;
    const int lane = tid & 63;
    const int q    = lane >> 4;
    const int l15  = lane & 15;

    if (bid < 256) {
        // ---- stage 16 tokens of x as f16 in LDS
        const int tb  = bid * 16;
        const int row = tid >> 4;
        const int cg  = tid & 15;
        const float* xr = x + (size_t)(tb + row) * DDIM;
#pragma unroll
        for (int i = 0; i < 8; ++i) {
            int col = cg * 4 + i * 64;
            float4 v = *(const float4*)(xr + col);
            f16x4 h = {(f16)v.x, (f16)v.y, (f16)v.z, (f16)v.w};
            *(f16x4*)&xs[row][col] = h;
        }
        __syncthreads();

        // ---- emit xh fragment slabs for K2
#pragma unroll
        for (int j = 0; j < 4; ++j) {
            int kt = wv * 4 + j;
            f16x8 vv = *(const f16x8*)&xs[l15][kt * 32 + q * 8];
            *(f16x8*)(xh + (size_t)(bid * 16 + kt) * 512 + lane * 8) = vv;
        }

        // ---- s: wave wv covers n-cols wv*16+l15 of both W2 (B) and W3 (C)
        const int ncol = wv * 16 + l15;
        f32x4 acc0 = (f32x4){0.f, 0.f, 0.f, 0.f};
        f32x4 acc1 = (f32x4){0.f, 0.f, 0.f, 0.f};
#pragma unroll
        for (int kt = 0; kt < 16; ++kt) {
            f16x8 a = *(const f16x8*)&xs[l15][kt * 32 + q * 8];
            const float* p2 = W2 + (size_t)(kt * 32 + q * 8) * 64 + ncol;
            const float* p3 = W3 + (size_t)(kt * 32 + q * 8) * 64 + ncol;
            f16x8 bB, bC;
#pragma unroll
            for (int j = 0; j < 8; ++j) {
                bB[j] = (f16)p2[j * 64];
                bC[j] = (f16)p3[j * 64];
            }
            acc0 = __builtin_amdgcn_mfma_f32_16x16x32_f16(a, bB, acc0, 0, 0, 0);
            acc1 = __builtin_amdgcn_mfma_f32_16x16x32_f16(a, bC, acc1, 0, 0, 0);
        }
        float b2v = b2[ncol];
        float b3v = b3[ncol];
#pragma unroll
        for (int r = 0; r < 4; ++r) {
            float p = (acc0[r] + b2v) * (acc1[r] + b3v);
            p += __shfl_xor(p, 1); p += __shfl_xor(p, 2);
            p += __shfl_xor(p, 4); p += __shfl_xor(p, 8);
            if (l15 == 0) sred[wv * 16 + q * 4 + r] = p;
        }
        __syncthreads();
        if (tid < 16)
            s_out[tb + tid] = sred[tid] + sred[16 + tid] + sred[32 + tid] + sred[48 + tid];
        return;
    }

    // ---- W1 strip wb: 512 k x 32 cols -> 32 fragment slabs of w1t
    const int wb = bid - 256;                    // 0..15
    const float* src = W1;
    const int col0 = wb * 32;
    f16* dst = w1t + (size_t)wb * 2 * 16 * 512;
#pragma unroll
    for (int i = 0; i < 16; ++i) {
        int f  = tid + 256 * i;
        int k  = f >> 3;
        int c4 = (f & 7) * 4;
        float4 v = *(const float4*)(src + (size_t)k * DDIM + col0 + c4);
        lt[c4 + 0][k] = (f16)v.x; lt[c4 + 1][k] = (f16)v.y;
        lt[c4 + 2][k] = (f16)v.z; lt[c4 + 3][k] = (f16)v.w;
    }
    __syncthreads();
#pragma unroll
    for (int j = 0; j < 8; ++j) {
        int s   = wv * 8 + j;                    // 0..31
        int ntL = s >> 4;
        int kt  = s & 15;
        f16x8 vv = *(const f16x8*)&lt[ntL * 16 + l15][kt * 32 + q * 8];
        *(f16x8*)(dst + (size_t)(ntL * 16 + kt) * 512 + lane * 8) = vv;
    }
}

// ---------------------------------------------------------------------------
// K2: zero-LDS register GEMM.  Grid (8, M/64) x 512 thr (8 waves).
// Wave wv: m-tile mt=wv&3 (16 tokens), n-tiles nh*2, nh*2+1.
// ---------------------------------------------------------------------------
__global__ __launch_bounds__(512) void k2_y(
    const f16* __restrict__ xh, const f16* __restrict__ w1t,
    const float* __restrict__ x, const float* __restrict__ b1,
    const float* __restrict__ s_in, float* __restrict__ y)
{
    const int tid  = threadIdx.x;
    const int wv   = tid >> 6;
    const int lane = tid & 63;
    const int q    = lane >> 4;
    const int l15  = lane & 15;
    const int mt   = wv & 3;
    const int nh   = wv >> 2;
    const int cB   = blockIdx.x;
    const int rB   = blockIdx.y;

    const f16* aP  = xh  + (size_t)((rB * 4 + mt) * 16) * 512 + lane * 8;
    const f16* bP0 = w1t + (size_t)((cB * 4 + nh * 2 + 0) * 16) * 512 + lane * 8;
    const f16* bP1 = w1t + (size_t)((cB * 4 + nh * 2 + 1) * 16) * 512 + lane * 8;

    f32x4 acc0 = (f32x4){0.f, 0.f, 0.f, 0.f};
    f32x4 acc1 = (f32x4){0.f, 0.f, 0.f, 0.f};
#pragma unroll
    for (int kt = 0; kt < 16; ++kt) {
        f16x8 a  = *(const f16x8*)(aP  + (size_t)kt * 512);
        f16x8 b0 = *(const f16x8*)(bP0 + (size_t)kt * 512);
        f16x8 bb = *(const f16x8*)(bP1 + (size_t)kt * 512);
        acc0 = __builtin_amdgcn_mfma_f32_16x16x32_f16(a, b0, acc0, 0, 0, 0);
        acc1 = __builtin_amdgcn_mfma_f32_16x16x32_f16(a, bb, acc1, 0, 0, 0);
    }

    const int d0 = cB * 64 + (nh * 2 + 0) * 16 + l15;
    const int d1 = cB * 64 + (nh * 2 + 1) * 16 + l15;
    const float bb0 = b1[d0], bb1 = b1[d1];
#pragma unroll
    for (int r = 0; r < 4; ++r) {
        int token = rB * 64 + mt * 16 + q * 4 + r;
        float st = s_in[token];
        const float* xr = x + (size_t)token * DDIM;
        float*       yr = y + (size_t)token * DDIM;
        yr[d0] = xr[d0] * softplusf(acc0[r] + bb0) * st;
        yr[d1] = xr[d1] * softplusf(acc1[r] + bb1) * st;
    }
}

// ---------------------------------------------------------------------------
extern "C" void kernel_launch(void* const* d_in, const int* in_sizes, int n_in,
                              void* d_out, int out_size, void* d_ws, size_t ws_size,
                              hipStream_t stream)
{
    (void)n_in; (void)out_size; (void)ws_size;
    const float* x  = (const float*)d_in[0];
    const float* W1 = (const float*)d_in[1];
    const float* b1 = (const float*)d_in[2];
    const float* W2 = (const float*)d_in[3];
    const float* b2 = (const float*)d_in[4];
    const float* W3 = (const float*)d_in[5];
    const float* b3 = (const float*)d_in[6];
    // d_in[7] = A unused (multiplies h=0)
    float* y = (float*)d_out;

    char* ws  = (char*)d_ws;
    f16* xh   = (f16*)(ws);                 // 4 MB   (256 tiles x 16 slabs)
    f16* w1t  = (f16*)(ws + (4 << 20));     // 512 KB (32 nt x 16 kt)
    float* sv = (float*)(ws + (5 << 20));   // 16 KB

    const int M = in_sizes[0] / DDIM;       // 4096

    k1_s_and_prep<<<272, 256, 0, stream>>>(x, W1, W2, b2, W3, b3, xh, w1t, sv);
    k2_y<<<dim3(8, M / 64), 512, 0, stream>>>(xh, w1t, x, b1, sv, y);
}

// Round 8
// 94.849 us; speedup vs baseline: 3.9032x; 1.0580x over previous
//
#include <hip/hip_runtime.h>
#include <math.h>

// B=2, L=2048, D=512, N=64 -> M=4096 tokens.
//   y[t,d] = x[t,d] * softplus((x@W1+b1)[t,d]) * s[t]
//   s[t]   = dot(x_t@W2+b2, x_t@W3+b3)
//   exp(delta*A) multiplies h=0 -> contributes zero; A unused.
//
// Best-measured structure (R5, 94.6 us; ~11.6 us controllable after the
// ~83 us harness reset stream).  Three launches:
//   prep_w  (20 blocks): W1/W2/W3 -> f16 fragment slabs (transpose via LDS)
//   s_kernel(256 blocks): x -> f16 LDS (+xh slabs for y), s[t] via MFMA with
//                         W2/W3 fragments direct global->VGPR (L2-hot)
//   y_kernel(512 blocks): zero-LDS register GEMM + softplus epilogue
// Failed alternatives (measured): cooperative fusion (grid.sync ~140us each,
// R6); register-built W2/W3 B-frags from strided fp32 (+6us VMEM issue, R7);
// LDS double-buffered slab staging (R4, +3us vs this).
//
// Fragment slab = 16(rows)x32(k) f16 tile as 1024 contiguous bytes in exact
// MFMA lane order (lane L=q*16+m holds row m, k=q*8..q*8+7) -> every wave
// fragment load is one fully-coalesced 1KB read.
#define DDIM 512

typedef _Float16 f16;
typedef _Float16 f16x4 __attribute__((ext_vector_type(4)));
typedef _Float16 f16x8 __attribute__((ext_vector_type(8)));
typedef float f32x4 __attribute__((ext_vector_type(4)));

__device__ __forceinline__ float softplusf(float v) {
    return (v > 20.0f) ? v : log1pf(__expf(v));
}

// ---------------------------------------------------------------------------
// prep_w: 20 blocks x 256 thr.  W1 -> w1t slabs (nt 0..31); W2 -> w23 nt 0..3;
// W3 -> w23 nt 4..7.  Each block transposes a 512k x 32col strip.
// ---------------------------------------------------------------------------
__global__ __launch_bounds__(256) void prep_w(
    const float* __restrict__ W1, const float* __restrict__ W2,
    const float* __restrict__ W3, f16* __restrict__ w1t, f16* __restrict__ w23)
{
    __shared__ __align__(16) f16 lt[32][520];
    const int tid  = threadIdx.x;
    const int wb   = blockIdx.x;
    const int wv   = tid >> 6;
    const int lane = tid & 63;
    const int q    = lane >> 4;
    const int l15  = lane & 15;

    const float* src; int srcRS, col0; f16* dst;
    if (wb < 16)      { src = W1; srcRS = DDIM; col0 = wb * 32;
                        dst = w1t + (size_t)wb * 2 * 16 * 512; }
    else if (wb < 18) { src = W2; srcRS = 64;  col0 = (wb - 16) * 32;
                        dst = w23 + (size_t)(wb - 16) * 2 * 16 * 512; }
    else              { src = W3; srcRS = 64;  col0 = (wb - 18) * 32;
                        dst = w23 + (size_t)(4 + (wb - 18) * 2) * 16 * 512; }
#pragma unroll
    for (int i = 0; i < 16; ++i) {
        int f  = tid + 256 * i;
        int k  = f >> 3;
        int c4 = (f & 7) * 4;
        float4 v = *(const float4*)(src + (size_t)k * srcRS + col0 + c4);
        lt[c4 + 0][k] = (f16)v.x; lt[c4 + 1][k] = (f16)v.y;
        lt[c4 + 2][k] = (f16)v.z; lt[c4 + 3][k] = (f16)v.w;
    }
    __syncthreads();
#pragma unroll
    for (int j = 0; j < 8; ++j) {
        int s   = wv * 8 + j;          // 0..31
        int ntL = s >> 4;              // 0..1
        int kt  = s & 15;
        f16x8 vv = *(const f16x8*)&lt[ntL * 16 + l15][kt * 32 + q * 8];
        *(f16x8*)(dst + (size_t)(ntL * 16 + kt) * 512 + lane * 8) = vv;
    }
}

// ---------------------------------------------------------------------------
// s_kernel: 256 blocks x 256 thr (4 waves), 16 tokens/block.
// Converts x->f16 (LDS staged, also written to xh slabs for y_kernel);
// w23 B-fragments load direct global->VGPR.  One barrier total.
// Wave wv: B at nt=wv, C at nt=4+wv.
// ---------------------------------------------------------------------------
__global__ __launch_bounds__(256) void s_kernel(
    const float* __restrict__ x, const f16* __restrict__ w23,
    const float* __restrict__ b2, const float* __restrict__ b3,
    f16* __restrict__ xh, float* __restrict__ s_out)
{
    __shared__ __align__(16) f16 xs[16][520];
    __shared__ float sred[64];

    const int tid  = threadIdx.x;
    const int wv   = tid >> 6;
    const int lane = tid & 63;
    const int q    = lane >> 4;
    const int l15  = lane & 15;
    const int mtG  = blockIdx.x;
    const int tb   = mtG * 16;

    // stage x: row=tid>>4, 8 strided float4 reads, convert, LDS write
    {
        const int row = tid >> 4, cg = tid & 15;
        const float* xr = x + (size_t)(tb + row) * DDIM;
#pragma unroll
        for (int i = 0; i < 8; ++i) {
            int col = cg * 4 + i * 64;
            float4 v = *(const float4*)(xr + col);
            f16x4 h = {(f16)v.x, (f16)v.y, (f16)v.z, (f16)v.w};
            *(f16x4*)&xs[row][col] = h;
        }
    }
    __syncthreads();

    // write xh fragment slabs (for y_kernel) while compute proceeds
#pragma unroll
    for (int j = 0; j < 4; ++j) {
        int kt = wv * 4 + j;
        f16x8 vv = *(const f16x8*)&xs[l15][kt * 32 + q * 8];
        *(f16x8*)(xh + (size_t)(mtG * 16 + kt) * 512 + lane * 8) = vv;
    }

    f32x4 acc0 = (f32x4){0.f, 0.f, 0.f, 0.f};
    f32x4 acc1 = (f32x4){0.f, 0.f, 0.f, 0.f};
    const f16* wB = w23 + (size_t)(wv    ) * 16 * 512 + lane * 8;
    const f16* wC = w23 + (size_t)(wv + 4) * 16 * 512 + lane * 8;
#pragma unroll
    for (int kt = 0; kt < 16; ++kt) {
        f16x8 a  = *(const f16x8*)&xs[l15][kt * 32 + q * 8];
        f16x8 bB = *(const f16x8*)(wB + (size_t)kt * 512);
        f16x8 bC = *(const f16x8*)(wC + (size_t)kt * 512);
        acc0 = __builtin_amdgcn_mfma_f32_16x16x32_f16(a, bB, acc0, 0, 0, 0);
        acc1 = __builtin_amdgcn_mfma_f32_16x16x32_f16(a, bC, acc1, 0, 0, 0);
    }

    // s partial over n = wv*16 + l15 ; token = q*4 + r
    float b2v = b2[wv * 16 + l15];
    float b3v = b3[wv * 16 + l15];
#pragma unroll
    for (int r = 0; r < 4; ++r) {
        float p = (acc0[r] + b2v) * (acc1[r] + b3v);
        p += __shfl_xor(p, 1); p += __shfl_xor(p, 2);
        p += __shfl_xor(p, 4); p += __shfl_xor(p, 8);
        if (l15 == 0) sred[wv * 16 + q * 4 + r] = p;
    }
    __syncthreads();
    if (tid < 16)
        s_out[tb + tid] = sred[tid] + sred[16 + tid] + sred[32 + tid] + sred[48 + tid];
}

// ---------------------------------------------------------------------------
// y_kernel: zero-LDS register GEMM.  Grid (8, M/64) x 512 thr (8 waves),
// 2 blocks/CU.  Wave wv: m-tile mt=wv&3 (16 tokens), n-tiles nh*2, nh*2+1.
// All fragments load direct global->VGPR from pre-swizzled slabs (L2-hot).
// ---------------------------------------------------------------------------
__global__ __launch_bounds__(512) void y_kernel(
    const f16* __restrict__ xh, const f16* __restrict__ w1t,
    const float* __restrict__ x, const float* __restrict__ b1,
    const float* __restrict__ s_in, float* __restrict__ y)
{
    const int tid  = threadIdx.x;
    const int wv   = tid >> 6;
    const int lane = tid & 63;
    const int q    = lane >> 4;
    const int l15  = lane & 15;
    const int mt   = wv & 3;
    const int nh   = wv >> 2;
    const int cB   = blockIdx.x;          // d-block (64 cols)
    const int rB   = blockIdx.y;          // token-block (64 rows)

    const f16* aP  = xh  + (size_t)((rB * 4 + mt) * 16) * 512 + lane * 8;
    const f16* bP0 = w1t + (size_t)((cB * 4 + nh * 2 + 0) * 16) * 512 + lane * 8;
    const f16* bP1 = w1t + (size_t)((cB * 4 + nh * 2 + 1) * 16) * 512 + lane * 8;

    f32x4 acc0 = (f32x4){0.f, 0.f, 0.f, 0.f};
    f32x4 acc1 = (f32x4){0.f, 0.f, 0.f, 0.f};
#pragma unroll
    for (int kt = 0; kt < 16; ++kt) {
        f16x8 a  = *(const f16x8*)(aP  + (size_t)kt * 512);
        f16x8 b0 = *(const f16x8*)(bP0 + (size_t)kt * 512);
        f16x8 b1v = *(const f16x8*)(bP1 + (size_t)kt * 512);
        acc0 = __builtin_amdgcn_mfma_f32_16x16x32_f16(a, b0,  acc0, 0, 0, 0);
        acc1 = __builtin_amdgcn_mfma_f32_16x16x32_f16(a, b1v, acc1, 0, 0, 0);
    }

    // epilogue: y = x_fp32 * softplus(acc + b1) * s
    const int d0 = cB * 64 + (nh * 2 + 0) * 16 + l15;
    const int d1 = cB * 64 + (nh * 2 + 1) * 16 + l15;
    const float bb0 = b1[d0], bb1 = b1[d1];
#pragma unroll
    for (int r = 0; r < 4; ++r) {
        int token = rB * 64 + mt * 16 + q * 4 + r;
        float st = s_in[token];
        const float* xr = x + (size_t)token * DDIM;
        float*       yr = y + (size_t)token * DDIM;
        yr[d0] = xr[d0] * softplusf(acc0[r] + bb0) * st;
        yr[d1] = xr[d1] * softplusf(acc1[r] + bb1) * st;
    }
}

// ---------------------------------------------------------------------------
extern "C" void kernel_launch(void* const* d_in, const int* in_sizes, int n_in,
                              void* d_out, int out_size, void* d_ws, size_t ws_size,
                              hipStream_t stream)
{
    (void)n_in; (void)out_size; (void)ws_size;
    const float* x  = (const float*)d_in[0];
    const float* W1 = (const float*)d_in[1];
    const float* b1 = (const float*)d_in[2];
    const float* W2 = (const float*)d_in[3];
    const float* b2 = (const float*)d_in[4];
    const float* W3 = (const float*)d_in[5];
    const float* b3 = (const float*)d_in[6];
    // d_in[7] = A unused (multiplies h=0)
    float* y = (float*)d_out;

    char* ws  = (char*)d_ws;
    f16* xh   = (f16*)(ws);                           // 4 MB   (M/16 x 16 slabs)
    f16* w1t  = (f16*)(ws + (4 << 20));               // 512 KB (32 nt x 16 kt)
    f16* w23  = (f16*)(ws + (4 << 20) + (512 << 10)); // 128 KB (8 nt x 16 kt)
    float* sv = (float*)(ws + (5 << 20));             // 16 KB

    const int M = in_sizes[0] / DDIM;                 // 4096

    prep_w<<<20, 256, 0, stream>>>(W1, W2, W3, w1t, w23);
    s_kernel<<<M / 16, 256, 0, stream>>>(x, w23, b2, b3, xh, sv);
    y_kernel<<<dim3(8, M / 64), 512, 0, stream>>>(xh, w1t, x, b1, sv, y);
}